// Round 3
// baseline (670.647 us; speedup 1.0000x reference)
//
#include <hip/hip_runtime.h>
#include <hip/hip_bf16.h>

#define D 64
#define D4 16            // float4s per row
#define RB 128           // rows per coarse bucket (power of two: b = row>>7)
#define RB_SHIFT 7
#define COL_BITS 18      // n_total = 150001 < 2^18
#define COL_MASK 0x3FFFF

// ---------------------------------------------------------------------------
// coarse histogram: counts[b] = #edges with row>>7 == b   (grid-stride, LDS hist)
__global__ void coarse_hist_kernel(const int* __restrict__ row, int* __restrict__ counts,
                                   int n_edges, int nb) {
    __shared__ int h[2048];
    for (int i = threadIdx.x; i < nb; i += blockDim.x) h[i] = 0;
    __syncthreads();
    int stride = gridDim.x * blockDim.x;
    for (int e = blockIdx.x * blockDim.x + threadIdx.x; e < n_edges; e += stride)
        atomicAdd(&h[row[e] >> RB_SHIFT], 1);
    __syncthreads();
    for (int i = threadIdx.x; i < nb; i += blockDim.x)
        if (h[i]) atomicAdd(&counts[i], h[i]);
}

// one-block exclusive scan of nb (<=2048) counts -> coff + ccursor, coff[nb]=total
__global__ void coarse_scan_kernel(const int* __restrict__ counts,
                                   int* __restrict__ coff, int* __restrict__ ccursor,
                                   int nb) {
    __shared__ int lds[256];
    int tid = threadIdx.x;
    int local[8];
    int sum = 0;
#pragma unroll
    for (int j = 0; j < 8; ++j) {
        int idx = tid * 8 + j;
        int v = (idx < nb) ? counts[idx] : 0;
        local[j] = sum;
        sum += v;
    }
    lds[tid] = sum;
    __syncthreads();
    for (int off = 1; off < 256; off <<= 1) {
        int v = (tid >= off) ? lds[tid - off] : 0;
        __syncthreads();
        lds[tid] += v;
        __syncthreads();
    }
    int prefix = (tid == 0) ? 0 : lds[tid - 1];
#pragma unroll
    for (int j = 0; j < 8; ++j) {
        int idx = tid * 8 + j;
        if (idx < nb) {
            int o = prefix + local[j];
            coff[idx] = o;
            ccursor[idx] = o;
        }
    }
    if (tid == 255) coff[nb] = lds[255];
}

// scatter edges into coarse buckets; pack (col, row_local) + val into int2
__global__ void fill_coarse_kernel(const int* __restrict__ row, const int* __restrict__ col,
                                   const float* __restrict__ val, int* __restrict__ ccursor,
                                   int2* __restrict__ stage, int n_edges) {
    int e = blockIdx.x * blockDim.x + threadIdx.x;
    if (e >= n_edges) return;
    int r = row[e];
    int b = r >> RB_SHIFT;
    int pos = atomicAdd(&ccursor[b], 1);
    stage[pos] = make_int2(col[e] | ((r & (RB - 1)) << COL_BITS), __float_as_int(val[e]));
}

// per-bucket: sort edges by row within the bucket's span, emit row-level offsets
__global__ void bucket_finalize_kernel(const int* __restrict__ coff,
                                       const int2* __restrict__ stage,
                                       int* __restrict__ offsets,
                                       int2* __restrict__ pairs,
                                       int n_total, int n_edges) {
    __shared__ int sc[RB];
    __shared__ int cur[RB];
    int b = blockIdx.x;
    int tid = threadIdx.x;
    int s = coff[b], e_end = coff[b + 1];
    if (tid < RB) sc[tid] = 0;
    __syncthreads();
    // pass 1: histogram of local rows
    for (int k = s + tid; k < e_end; k += blockDim.x)
        atomicAdd(&sc[stage[k].x >> COL_BITS], 1);
    __syncthreads();
    // inclusive scan of 128 counters (Hillis-Steele, full-block barriers)
    for (int off = 1; off < RB; off <<= 1) {
        int v = (tid < RB && tid >= off) ? sc[tid - off] : 0;
        __syncthreads();
        if (tid < RB) sc[tid] += v;
        __syncthreads();
    }
    // row-level offsets + local cursors (exclusive prefix)
    if (tid < RB) {
        int excl = (tid == 0) ? 0 : sc[tid - 1];
        int r = b * RB + tid;
        if (r < n_total) offsets[r] = s + excl;
        cur[tid] = s + excl;
    }
    __syncthreads();
    // pass 2: scatter within span (span is contiguous & L2-hot)
    for (int k = s + tid; k < e_end; k += blockDim.x) {
        int2 p = stage[k];
        int rl = p.x >> COL_BITS;
        int pos = atomicAdd(&cur[rl], 1);
        pairs[pos] = make_int2(p.x & COL_MASK, p.y);
    }
    if (b == 0 && tid == 0) offsets[n_total] = n_edges;
}

// ---------------------------------------------------------------------------
// gather spmm: one wave per destination row; 4 groups of 16 lanes cover 4 edges
// per iteration, each group spans the 64-float row as float4s. No atomics.
template <bool SPLIT>
__global__ void spmm_gather_kernel(const int* __restrict__ offsets,
                                   const int2* __restrict__ pairs,
                                   const float* __restrict__ srcA,
                                   const float* __restrict__ srcB,
                                   int n_user,
                                   float* __restrict__ dst, int n_total) {
    int wid = threadIdx.x >> 6;
    int lane = threadIdx.x & 63;
    int r = blockIdx.x * 4 + wid;
    if (r >= n_total) return;
    int start = offsets[r];
    int end = offsets[r + 1];
    int g = lane >> 4;
    int sub = lane & 15;
    float4 acc = make_float4(0.f, 0.f, 0.f, 0.f);
    const float4* a4 = reinterpret_cast<const float4*>(srcA);
    const float4* b4 = reinterpret_cast<const float4*>(srcB);
    for (int k = start + g; k < end; k += 4) {
        int2 p = pairs[k];
        float w = __int_as_float(p.y);
        int c = p.x;
        float4 m;
        if (SPLIT) {
            m = (c < n_user) ? a4[(size_t)c * D4 + sub]
                             : b4[(size_t)(c - n_user) * D4 + sub];
        } else {
            m = a4[(size_t)c * D4 + sub];
        }
        acc.x += w * m.x; acc.y += w * m.y; acc.z += w * m.z; acc.w += w * m.w;
    }
    acc.x += __shfl_xor(acc.x, 16, 64);
    acc.y += __shfl_xor(acc.y, 16, 64);
    acc.z += __shfl_xor(acc.z, 16, 64);
    acc.w += __shfl_xor(acc.w, 16, 64);
    acc.x += __shfl_xor(acc.x, 32, 64);
    acc.y += __shfl_xor(acc.y, 32, 64);
    acc.z += __shfl_xor(acc.z, 32, 64);
    acc.w += __shfl_xor(acc.w, 32, 64);
    if (g == 0) reinterpret_cast<float4*>(dst)[(size_t)r * D4 + sub] = acc;
}

// ---------------------------------------------------------------------------
// layer 0: write batch rows straight from the source tables (no concat needed)
__global__ void gather_init_kernel(const int* __restrict__ users,
                                   const int* __restrict__ items,
                                   const float* __restrict__ user_emb,
                                   const float* __restrict__ item_emb,
                                   float* __restrict__ u_acc,
                                   float* __restrict__ v_acc, int batch) {
    int t = blockIdx.x * blockDim.x + threadIdx.x;
    int b = t >> 4;
    int sub = t & 15;
    if (b >= batch) return;
    reinterpret_cast<float4*>(u_acc)[(size_t)b * D4 + sub] =
        reinterpret_cast<const float4*>(user_emb)[(size_t)users[b] * D4 + sub];
    reinterpret_cast<float4*>(v_acc)[(size_t)b * D4 + sub] =
        reinterpret_cast<const float4*>(item_emb)[(size_t)items[b] * D4 + sub];
}

// layers 1,2: accumulate batch rows from buf
__global__ void gather_acc_kernel(const int* __restrict__ users,
                                  const int* __restrict__ items,
                                  const float* __restrict__ buf,
                                  float* __restrict__ u_acc,
                                  float* __restrict__ v_acc,
                                  int batch, int n_user_rows) {
    int t = blockIdx.x * blockDim.x + threadIdx.x;
    int b = t >> 4;
    int sub = t & 15;
    if (b >= batch) return;
    float4 uu = reinterpret_cast<const float4*>(buf)[(size_t)users[b] * D4 + sub];
    float4 vv = reinterpret_cast<const float4*>(buf)[(size_t)(n_user_rows + items[b]) * D4 + sub];
    float4* up = reinterpret_cast<float4*>(u_acc) + (size_t)b * D4 + sub;
    float4* vp = reinterpret_cast<float4*>(v_acc) + (size_t)b * D4 + sub;
    float4 a = *up, c = *vp;
    a.x += uu.x; a.y += uu.y; a.z += uu.z; a.w += uu.w;
    c.x += vv.x; c.y += vv.y; c.z += vv.z; c.w += vv.w;
    *up = a;
    *vp = c;
}

// layer 3 gather fused with dot + BCE loss
__global__ void gather_loss_kernel(const int* __restrict__ users,
                                   const int* __restrict__ items,
                                   const float* __restrict__ buf,
                                   const float* __restrict__ u_acc,
                                   const float* __restrict__ v_acc,
                                   const float* __restrict__ labels,
                                   float* __restrict__ out,
                                   int batch, int n_user_rows) {
    int t = blockIdx.x * blockDim.x + threadIdx.x;
    int b = t >> 4;
    int sub = t & 15;
    float partial = 0.0f;
    if (b < batch) {
        float4 uu = reinterpret_cast<const float4*>(buf)[(size_t)users[b] * D4 + sub];
        float4 vv = reinterpret_cast<const float4*>(buf)[(size_t)(n_user_rows + items[b]) * D4 + sub];
        float4 a = reinterpret_cast<const float4*>(u_acc)[(size_t)b * D4 + sub];
        float4 c = reinterpret_cast<const float4*>(v_acc)[(size_t)b * D4 + sub];
        a.x += uu.x; a.y += uu.y; a.z += uu.z; a.w += uu.w;
        c.x += vv.x; c.y += vv.y; c.z += vv.z; c.w += vv.w;
        partial = a.x * c.x + a.y * c.y + a.z * c.z + a.w * c.w;
    }
    // reduce dot over the 16 lanes of this b
    partial += __shfl_xor(partial, 1, 64);
    partial += __shfl_xor(partial, 2, 64);
    partial += __shfl_xor(partial, 4, 64);
    partial += __shfl_xor(partial, 8, 64);
    float lb = 0.0f;
    if (b < batch && sub == 0) {
        float g = partial * (1.0f / 16.0f);   // (sum/4).(sum/4)
        float y = labels[b];
        lb = fmaxf(g, 0.0f) - g * y + log1pf(expf(-fabsf(g)));
    }
    // sum the 4 b-leaders in this wave
    lb += __shfl_xor(lb, 16, 64);
    lb += __shfl_xor(lb, 32, 64);
    __shared__ float sd[4];
    int wid = threadIdx.x >> 6;
    if ((threadIdx.x & 63) == 0) sd[wid] = lb;
    __syncthreads();
    if (threadIdx.x == 0)
        atomicAdd(out, (sd[0] + sd[1] + sd[2] + sd[3]) / (float)batch);
}

// ---------------------------------------------------------------------------
extern "C" void kernel_launch(void* const* d_in, const int* in_sizes, int n_in,
                              void* d_out, int out_size, void* d_ws, size_t ws_size,
                              hipStream_t stream) {
    const int* users = (const int*)d_in[0];
    const int* items = (const int*)d_in[1];
    const float* labels = (const float*)d_in[2];
    const int* edge_row = (const int*)d_in[3];
    const int* edge_col = (const int*)d_in[4];
    const float* edge_val = (const float*)d_in[5];
    const float* user_emb = (const float*)d_in[6];
    const float* item_emb = (const float*)d_in[7];

    const int batch = in_sizes[0];
    const int n_edges = in_sizes[3];
    const int n_user_rows = in_sizes[6] / D;   // 100001
    const int n_item_rows = in_sizes[7] / D;   // 50000
    const int n_total = n_user_rows + n_item_rows;
    const int nb = (n_total + RB - 1) / RB;    // 1172 coarse buckets

    auto align256 = [](size_t x) { return (x + 255) & ~(size_t)255; };
    const size_t table_bytes = align256((size_t)n_total * D * sizeof(float));  // 38.4 MB
    const size_t acc_bytes = align256((size_t)batch * D * sizeof(float));      // 2 MB
    const size_t off_bytes = align256((size_t)(n_total + 1) * sizeof(int));    // 600 KB
    const size_t pairs_bytes = align256((size_t)n_edges * sizeof(int2));       // 16 MB
    const size_t nb_bytes = align256((size_t)(nb + 1) * sizeof(int));

    char* ws = (char*)d_ws;
    float* buf0   = (float*)ws;                 ws += table_bytes;
    float* buf1   = (float*)ws;                 ws += table_bytes;
    float* u_acc  = (float*)ws;                 ws += acc_bytes;
    float* v_acc  = (float*)ws;                 ws += acc_bytes;
    int*   offsets= (int*)ws;                   ws += off_bytes;
    int2*  pairs  = (int2*)ws;                  ws += pairs_bytes;
    // stage is dead before buf0's first write (spmm layer 1) -> alias into buf0
    int2*  stage  = (int2*)buf0;
    // small bucket arrays are dead before buf1's first write (spmm layer 2)
    int*   counts = (int*)buf1;
    int*   coff   = (int*)((char*)buf1 + nb_bytes);
    int*   ccursor= (int*)((char*)buf1 + 2 * nb_bytes);

    hipMemsetAsync(counts, 0, (size_t)nb * sizeof(int), stream);
    hipMemsetAsync(d_out, 0, sizeof(float) * out_size, stream);

    // ---- CSR build (two-level binning) ----
    const int eb = (n_edges + 255) / 256;
    coarse_hist_kernel<<<256, 256, 0, stream>>>(edge_row, counts, n_edges, nb);
    coarse_scan_kernel<<<1, 256, 0, stream>>>(counts, coff, ccursor, nb);
    fill_coarse_kernel<<<eb, 256, 0, stream>>>(edge_row, edge_col, edge_val,
                                               ccursor, stage, n_edges);
    bucket_finalize_kernel<<<nb, 256, 0, stream>>>(coff, stage, offsets, pairs,
                                                   n_total, n_edges);

    // ---- layer 0 batch gather (straight from source tables) ----
    const int ga_blocks = (batch * 16 + 255) / 256;
    gather_init_kernel<<<ga_blocks, 256, 0, stream>>>(users, items, user_emb, item_emb,
                                                      u_acc, v_acc, batch);

    // ---- 3 propagation layers ----
    const int rows_blocks = (n_total + 3) / 4;
    // layer 1: split sources -> buf0 (stage is dead now)
    spmm_gather_kernel<true><<<rows_blocks, 256, 0, stream>>>(
        offsets, pairs, user_emb, item_emb, n_user_rows, buf0, n_total);
    gather_acc_kernel<<<ga_blocks, 256, 0, stream>>>(users, items, buf0,
                                                     u_acc, v_acc, batch, n_user_rows);
    // layer 2: buf0 -> buf1 (bucket arrays dead now)
    spmm_gather_kernel<false><<<rows_blocks, 256, 0, stream>>>(
        offsets, pairs, buf0, nullptr, 0, buf1, n_total);
    gather_acc_kernel<<<ga_blocks, 256, 0, stream>>>(users, items, buf1,
                                                     u_acc, v_acc, batch, n_user_rows);
    // layer 3: buf1 -> buf0, gather fused with loss
    spmm_gather_kernel<false><<<rows_blocks, 256, 0, stream>>>(
        offsets, pairs, buf1, nullptr, 0, buf0, n_total);
    gather_loss_kernel<<<ga_blocks, 256, 0, stream>>>(users, items, buf0, u_acc, v_acc,
                                                      labels, (float*)d_out,
                                                      batch, n_user_rows);
}

// Round 4
// 363.005 us; speedup vs baseline: 1.8475x; 1.8475x over previous
//
#include <hip/hip_runtime.h>
#include <hip/hip_bf16.h>

#define D 64
#define D4 16            // float4s per row
#define RB 128           // rows per coarse bucket (b = row>>7)
#define RB_SHIFT 7
#define COL_BITS 18      // n_total = 150001 < 2^18
#define COL_MASK 0x3FFFF
#define CHUNK 16384      // edges per partition block
#define SCAN_CHUNK 2048

// ---------------------------------------------------------------------------
// Pass A: per-chunk histogram over coarse buckets, stored bucket-major:
// base[b * nblk + blk] = #edges of chunk blk landing in bucket b
__global__ void hist2_kernel(const int* __restrict__ row, int* __restrict__ base,
                             int n_edges, int nb, int nblk) {
    __shared__ int h[2048];
    for (int i = threadIdx.x; i < nb; i += blockDim.x) h[i] = 0;
    __syncthreads();
    int blk = blockIdx.x;
    int s = blk * CHUNK;
    int e = min(s + CHUNK, n_edges);
    for (int k = s + threadIdx.x; k < e; k += blockDim.x)
        atomicAdd(&h[row[k] >> RB_SHIFT], 1);
    __syncthreads();
    for (int i = threadIdx.x; i < nb; i += blockDim.x)
        base[i * nblk + blk] = h[i];
}

// Pass B: exclusive scan, IN PLACE on `data` (each idx read+written by the same
// thread; cross-block ranges disjoint). 2048 elems per block of 256 threads.
__global__ void scan_block_kernel(int* data, int* blocksums, int n) {
    __shared__ int lds[256];
    int bas = blockIdx.x * SCAN_CHUNK;
    int tid = threadIdx.x;
    int local[8];
    int sum = 0;
#pragma unroll
    for (int j = 0; j < 8; ++j) {
        int idx = bas + tid * 8 + j;
        int v = (idx < n) ? data[idx] : 0;
        local[j] = sum;
        sum += v;
    }
    lds[tid] = sum;
    __syncthreads();
    for (int off = 1; off < 256; off <<= 1) {
        int v = (tid >= off) ? lds[tid - off] : 0;
        __syncthreads();
        lds[tid] += v;
        __syncthreads();
    }
    int prefix = (tid == 0) ? 0 : lds[tid - 1];
    if (tid == 255) blocksums[blockIdx.x] = lds[255];
#pragma unroll
    for (int j = 0; j < 8; ++j) {
        int idx = bas + tid * 8 + j;
        if (idx < n) data[idx] = prefix + local[j];
    }
}

__global__ void scan_sums_kernel(int* blocksums, int nblocks, int* data, int n) {
    if (threadIdx.x == 0 && blockIdx.x == 0) {
        int run = 0;
        for (int i = 0; i < nblocks; ++i) {
            int v = blocksums[i];
            blocksums[i] = run;
            run += v;
        }
        data[n] = run;  // total = n_edges
    }
}

__global__ void scan_add_kernel(int* data, const int* __restrict__ blocksums, int n) {
    int idx = blockIdx.x * blockDim.x + threadIdx.x;
    if (idx < n) data[idx] += blocksums[idx / SCAN_CHUNK];
}

// Pass C: re-read chunk, rank via block-private LDS cursors (no global atomics),
// write packed (col | row_local<<18, val) to exact position.
__global__ void fill_exact_kernel(const int* __restrict__ row, const int* __restrict__ col,
                                  const float* __restrict__ val, const int* __restrict__ base,
                                  int2* __restrict__ stage, int n_edges, int nb, int nblk) {
    __shared__ int cur[2048];
    int blk = blockIdx.x;
    for (int i = threadIdx.x; i < nb; i += blockDim.x)
        cur[i] = base[i * nblk + blk];
    __syncthreads();
    int s = blk * CHUNK;
    int e = min(s + CHUNK, n_edges);
    for (int k = s + threadIdx.x; k < e; k += blockDim.x) {
        int r = row[k];
        int b = r >> RB_SHIFT;
        int pos = atomicAdd(&cur[b], 1);
        stage[pos] = make_int2(col[k] | ((r & (RB - 1)) << COL_BITS), __float_as_int(val[k]));
    }
}

// per-bucket: sort edges by row within the bucket's span, emit row-level offsets
__global__ void bucket_finalize_kernel(const int* __restrict__ base, int nblk,
                                       const int2* __restrict__ stage,
                                       int* __restrict__ offsets,
                                       int2* __restrict__ pairs,
                                       int n_total, int n_edges) {
    __shared__ int sc[RB];
    __shared__ int cur[RB];
    int b = blockIdx.x;
    int tid = threadIdx.x;
    int s = base[b * nblk];
    int e_end = base[(b + 1) * nblk];  // b==nb-1 reads base[nb*nblk] = n_edges
    if (tid < RB) sc[tid] = 0;
    __syncthreads();
    for (int k = s + tid; k < e_end; k += blockDim.x)
        atomicAdd(&sc[stage[k].x >> COL_BITS], 1);
    __syncthreads();
    for (int off = 1; off < RB; off <<= 1) {
        int v = (tid < RB && tid >= off) ? sc[tid - off] : 0;
        __syncthreads();
        if (tid < RB) sc[tid] += v;
        __syncthreads();
    }
    if (tid < RB) {
        int excl = (tid == 0) ? 0 : sc[tid - 1];
        int r = b * RB + tid;
        if (r < n_total) offsets[r] = s + excl;
        cur[tid] = s + excl;
    }
    __syncthreads();
    for (int k = s + tid; k < e_end; k += blockDim.x) {
        int2 p = stage[k];
        int rl = p.x >> COL_BITS;
        int pos = atomicAdd(&cur[rl], 1);
        pairs[pos] = make_int2(p.x & COL_MASK, p.y);
    }
    if (b == 0 && tid == 0) offsets[n_total] = n_edges;
}

// ---------------------------------------------------------------------------
// gather spmm: one wave per destination row; 4 groups of 16 lanes cover 4 edges
// per iteration, each group spans the 64-float row as float4s. No atomics.
template <bool SPLIT>
__global__ void spmm_gather_kernel(const int* __restrict__ offsets,
                                   const int2* __restrict__ pairs,
                                   const float* __restrict__ srcA,
                                   const float* __restrict__ srcB,
                                   int n_user,
                                   float* __restrict__ dst, int n_total) {
    int wid = threadIdx.x >> 6;
    int lane = threadIdx.x & 63;
    int r = blockIdx.x * 4 + wid;
    if (r >= n_total) return;
    int start = offsets[r];
    int end = offsets[r + 1];
    int g = lane >> 4;
    int sub = lane & 15;
    float4 acc = make_float4(0.f, 0.f, 0.f, 0.f);
    const float4* a4 = reinterpret_cast<const float4*>(srcA);
    const float4* b4 = reinterpret_cast<const float4*>(srcB);
    for (int k = start + g; k < end; k += 4) {
        int2 p = pairs[k];
        float w = __int_as_float(p.y);
        int c = p.x;
        float4 m;
        if (SPLIT) {
            m = (c < n_user) ? a4[(size_t)c * D4 + sub]
                             : b4[(size_t)(c - n_user) * D4 + sub];
        } else {
            m = a4[(size_t)c * D4 + sub];
        }
        acc.x += w * m.x; acc.y += w * m.y; acc.z += w * m.z; acc.w += w * m.w;
    }
    acc.x += __shfl_xor(acc.x, 16, 64);
    acc.y += __shfl_xor(acc.y, 16, 64);
    acc.z += __shfl_xor(acc.z, 16, 64);
    acc.w += __shfl_xor(acc.w, 16, 64);
    acc.x += __shfl_xor(acc.x, 32, 64);
    acc.y += __shfl_xor(acc.y, 32, 64);
    acc.z += __shfl_xor(acc.z, 32, 64);
    acc.w += __shfl_xor(acc.w, 32, 64);
    if (g == 0) reinterpret_cast<float4*>(dst)[(size_t)r * D4 + sub] = acc;
}

// ---------------------------------------------------------------------------
// layer 0: write batch rows straight from the source tables
__global__ void gather_init_kernel(const int* __restrict__ users,
                                   const int* __restrict__ items,
                                   const float* __restrict__ user_emb,
                                   const float* __restrict__ item_emb,
                                   float* __restrict__ u_acc,
                                   float* __restrict__ v_acc, int batch) {
    int t = blockIdx.x * blockDim.x + threadIdx.x;
    int b = t >> 4;
    int sub = t & 15;
    if (b >= batch) return;
    reinterpret_cast<float4*>(u_acc)[(size_t)b * D4 + sub] =
        reinterpret_cast<const float4*>(user_emb)[(size_t)users[b] * D4 + sub];
    reinterpret_cast<float4*>(v_acc)[(size_t)b * D4 + sub] =
        reinterpret_cast<const float4*>(item_emb)[(size_t)items[b] * D4 + sub];
}

// layers 1,2: accumulate batch rows from buf
__global__ void gather_acc_kernel(const int* __restrict__ users,
                                  const int* __restrict__ items,
                                  const float* __restrict__ buf,
                                  float* __restrict__ u_acc,
                                  float* __restrict__ v_acc,
                                  int batch, int n_user_rows) {
    int t = blockIdx.x * blockDim.x + threadIdx.x;
    int b = t >> 4;
    int sub = t & 15;
    if (b >= batch) return;
    float4 uu = reinterpret_cast<const float4*>(buf)[(size_t)users[b] * D4 + sub];
    float4 vv = reinterpret_cast<const float4*>(buf)[(size_t)(n_user_rows + items[b]) * D4 + sub];
    float4* up = reinterpret_cast<float4*>(u_acc) + (size_t)b * D4 + sub;
    float4* vp = reinterpret_cast<float4*>(v_acc) + (size_t)b * D4 + sub;
    float4 a = *up, c = *vp;
    a.x += uu.x; a.y += uu.y; a.z += uu.z; a.w += uu.w;
    c.x += vv.x; c.y += vv.y; c.z += vv.z; c.w += vv.w;
    *up = a;
    *vp = c;
}

// layer 3 gather fused with dot + BCE loss
__global__ void gather_loss_kernel(const int* __restrict__ users,
                                   const int* __restrict__ items,
                                   const float* __restrict__ buf,
                                   const float* __restrict__ u_acc,
                                   const float* __restrict__ v_acc,
                                   const float* __restrict__ labels,
                                   float* __restrict__ out,
                                   int batch, int n_user_rows) {
    int t = blockIdx.x * blockDim.x + threadIdx.x;
    int b = t >> 4;
    int sub = t & 15;
    float partial = 0.0f;
    if (b < batch) {
        float4 uu = reinterpret_cast<const float4*>(buf)[(size_t)users[b] * D4 + sub];
        float4 vv = reinterpret_cast<const float4*>(buf)[(size_t)(n_user_rows + items[b]) * D4 + sub];
        float4 a = reinterpret_cast<const float4*>(u_acc)[(size_t)b * D4 + sub];
        float4 c = reinterpret_cast<const float4*>(v_acc)[(size_t)b * D4 + sub];
        a.x += uu.x; a.y += uu.y; a.z += uu.z; a.w += uu.w;
        c.x += vv.x; c.y += vv.y; c.z += vv.z; c.w += vv.w;
        partial = a.x * c.x + a.y * c.y + a.z * c.z + a.w * c.w;
    }
    partial += __shfl_xor(partial, 1, 64);
    partial += __shfl_xor(partial, 2, 64);
    partial += __shfl_xor(partial, 4, 64);
    partial += __shfl_xor(partial, 8, 64);
    float lb = 0.0f;
    if (b < batch && sub == 0) {
        float g = partial * (1.0f / 16.0f);
        float y = labels[b];
        lb = fmaxf(g, 0.0f) - g * y + log1pf(expf(-fabsf(g)));
    }
    lb += __shfl_xor(lb, 16, 64);
    lb += __shfl_xor(lb, 32, 64);
    __shared__ float sd[4];
    int wid = threadIdx.x >> 6;
    if ((threadIdx.x & 63) == 0) sd[wid] = lb;
    __syncthreads();
    if (threadIdx.x == 0)
        atomicAdd(out, (sd[0] + sd[1] + sd[2] + sd[3]) / (float)batch);
}

// ---------------------------------------------------------------------------
extern "C" void kernel_launch(void* const* d_in, const int* in_sizes, int n_in,
                              void* d_out, int out_size, void* d_ws, size_t ws_size,
                              hipStream_t stream) {
    const int* users = (const int*)d_in[0];
    const int* items = (const int*)d_in[1];
    const float* labels = (const float*)d_in[2];
    const int* edge_row = (const int*)d_in[3];
    const int* edge_col = (const int*)d_in[4];
    const float* edge_val = (const float*)d_in[5];
    const float* user_emb = (const float*)d_in[6];
    const float* item_emb = (const float*)d_in[7];

    const int batch = in_sizes[0];
    const int n_edges = in_sizes[3];
    const int n_user_rows = in_sizes[6] / D;   // 100001
    const int n_item_rows = in_sizes[7] / D;   // 50000
    const int n_total = n_user_rows + n_item_rows;
    const int nb = (n_total + RB - 1) / RB;    // 1172 coarse buckets
    const int nblk = (n_edges + CHUNK - 1) / CHUNK;  // 123 partition blocks
    const int L = nb * nblk;                    // 144156 hist entries

    auto align256 = [](size_t x) { return (x + 255) & ~(size_t)255; };
    const size_t table_bytes = align256((size_t)n_total * D * sizeof(float));  // 38.4 MB
    const size_t acc_bytes = align256((size_t)batch * D * sizeof(float));      // 2 MB
    const size_t off_bytes = align256((size_t)(n_total + 1) * sizeof(int));    // 600 KB
    const size_t pairs_bytes = align256((size_t)n_edges * sizeof(int2));       // 16 MB
    const size_t base_bytes = align256((size_t)(L + 1) * sizeof(int));         // 577 KB

    char* ws = (char*)d_ws;
    float* buf0   = (float*)ws;                 ws += table_bytes;
    float* buf1   = (float*)ws;                 ws += table_bytes;
    float* u_acc  = (float*)ws;                 ws += acc_bytes;
    float* v_acc  = (float*)ws;                 ws += acc_bytes;
    int*   offsets= (int*)ws;                   ws += off_bytes;
    int2*  pairs  = (int2*)ws;                  ws += pairs_bytes;
    // stage is dead before buf0's first write (spmm layer 1) -> alias into buf0
    int2*  stage  = (int2*)buf0;
    // hist/scan arrays are dead before buf1's first write (spmm layer 2)
    int*   base   = (int*)buf1;
    int*   bsums  = (int*)((char*)buf1 + base_bytes);

    hipMemsetAsync(d_out, 0, sizeof(float) * out_size, stream);

    // ---- CSR build: exact-offset two-level binning, no global atomics ----
    hist2_kernel<<<nblk, 256, 0, stream>>>(edge_row, base, n_edges, nb, nblk);
    const int nscan = (L + SCAN_CHUNK - 1) / SCAN_CHUNK;  // 71
    scan_block_kernel<<<nscan, 256, 0, stream>>>(base, bsums, L);
    scan_sums_kernel<<<1, 64, 0, stream>>>(bsums, nscan, base, L);
    scan_add_kernel<<<(L + 255) / 256, 256, 0, stream>>>(base, bsums, L);
    fill_exact_kernel<<<nblk, 256, 0, stream>>>(edge_row, edge_col, edge_val,
                                                base, stage, n_edges, nb, nblk);
    bucket_finalize_kernel<<<nb, 256, 0, stream>>>(base, nblk, stage, offsets, pairs,
                                                   n_total, n_edges);

    // ---- layer 0 batch gather ----
    const int ga_blocks = (batch * 16 + 255) / 256;
    gather_init_kernel<<<ga_blocks, 256, 0, stream>>>(users, items, user_emb, item_emb,
                                                      u_acc, v_acc, batch);

    // ---- 3 propagation layers ----
    const int rows_blocks = (n_total + 3) / 4;
    spmm_gather_kernel<true><<<rows_blocks, 256, 0, stream>>>(
        offsets, pairs, user_emb, item_emb, n_user_rows, buf0, n_total);
    gather_acc_kernel<<<ga_blocks, 256, 0, stream>>>(users, items, buf0,
                                                     u_acc, v_acc, batch, n_user_rows);
    spmm_gather_kernel<false><<<rows_blocks, 256, 0, stream>>>(
        offsets, pairs, buf0, nullptr, 0, buf1, n_total);
    gather_acc_kernel<<<ga_blocks, 256, 0, stream>>>(users, items, buf1,
                                                     u_acc, v_acc, batch, n_user_rows);
    spmm_gather_kernel<false><<<rows_blocks, 256, 0, stream>>>(
        offsets, pairs, buf1, nullptr, 0, buf0, n_total);
    gather_loss_kernel<<<ga_blocks, 256, 0, stream>>>(users, items, buf0, u_acc, v_acc,
                                                      labels, (float*)d_out,
                                                      batch, n_user_rows);
}

// Round 5
// 300.908 us; speedup vs baseline: 2.2287x; 1.2064x over previous
//
#include <hip/hip_runtime.h>
#include <hip/hip_bf16.h>

#define D 64
#define RB 128           // rows per coarse bucket (b = row>>7)
#define RB_SHIFT 7
#define COL_BITS 18      // n_total = 150001 < 2^18
#define COL_MASK 0x3FFFF
#define CHUNK 16384      // edges per partition block
#define SCAN_CHUNK 2048

// bf16 helpers (round-to-nearest-even via bit trick; bf16->f32 exact)
__device__ __forceinline__ unsigned f2bf(float f) {
    unsigned u = __float_as_uint(f);
    u += 0x7fff + ((u >> 16) & 1);
    return u >> 16;
}
__device__ __forceinline__ float bf2f(unsigned h) {
    return __uint_as_float(h << 16);
}

// ---------------------------------------------------------------------------
// one-time: concat f32 tables -> bf16 table (n_total x 64)
__global__ void convert_kernel(const float* __restrict__ user_emb,
                               const float* __restrict__ item_emb,
                               unsigned short* __restrict__ tbl,
                               int n_user_rows, int n_total) {
    size_t t = (size_t)blockIdx.x * blockDim.x + threadIdx.x;
    size_t total4 = (size_t)n_total * (D / 4);
    size_t user4 = (size_t)n_user_rows * (D / 4);
    for (size_t i = t; i < total4; i += (size_t)gridDim.x * blockDim.x) {
        float4 v = (i < user4) ? reinterpret_cast<const float4*>(user_emb)[i]
                               : reinterpret_cast<const float4*>(item_emb)[i - user4];
        uint2 o;
        o.x = f2bf(v.x) | (f2bf(v.y) << 16);
        o.y = f2bf(v.z) | (f2bf(v.w) << 16);
        reinterpret_cast<uint2*>(tbl)[i] = o;
    }
}

// ---------------------------------------------------------------------------
// Pass A: per-chunk histogram over coarse buckets, stored bucket-major
__global__ void hist2_kernel(const int* __restrict__ row, int* __restrict__ base,
                             int n_edges, int nb, int nblk) {
    __shared__ int h[2048];
    for (int i = threadIdx.x; i < nb; i += blockDim.x) h[i] = 0;
    __syncthreads();
    int blk = blockIdx.x;
    int s = blk * CHUNK;
    int e = min(s + CHUNK, n_edges);
    for (int k = s + threadIdx.x; k < e; k += blockDim.x)
        atomicAdd(&h[row[k] >> RB_SHIFT], 1);
    __syncthreads();
    for (int i = threadIdx.x; i < nb; i += blockDim.x)
        base[i * nblk + blk] = h[i];
}

// Pass B: exclusive scan, in place
__global__ void scan_block_kernel(int* data, int* blocksums, int n) {
    __shared__ int lds[256];
    int bas = blockIdx.x * SCAN_CHUNK;
    int tid = threadIdx.x;
    int local[8];
    int sum = 0;
#pragma unroll
    for (int j = 0; j < 8; ++j) {
        int idx = bas + tid * 8 + j;
        int v = (idx < n) ? data[idx] : 0;
        local[j] = sum;
        sum += v;
    }
    lds[tid] = sum;
    __syncthreads();
    for (int off = 1; off < 256; off <<= 1) {
        int v = (tid >= off) ? lds[tid - off] : 0;
        __syncthreads();
        lds[tid] += v;
        __syncthreads();
    }
    int prefix = (tid == 0) ? 0 : lds[tid - 1];
    if (tid == 255) blocksums[blockIdx.x] = lds[255];
#pragma unroll
    for (int j = 0; j < 8; ++j) {
        int idx = bas + tid * 8 + j;
        if (idx < n) data[idx] = prefix + local[j];
    }
}

__global__ void scan_sums_kernel(int* blocksums, int nblocks, int* data, int n) {
    if (threadIdx.x == 0 && blockIdx.x == 0) {
        int run = 0;
        for (int i = 0; i < nblocks; ++i) {
            int v = blocksums[i];
            blocksums[i] = run;
            run += v;
        }
        data[n] = run;  // total = n_edges
    }
}

__global__ void scan_add_kernel(int* data, const int* __restrict__ blocksums, int n) {
    int idx = blockIdx.x * blockDim.x + threadIdx.x;
    if (idx < n) data[idx] += blocksums[idx / SCAN_CHUNK];
}

// Pass C: rank via block-private LDS cursors, write to exact positions
__global__ void fill_exact_kernel(const int* __restrict__ row, const int* __restrict__ col,
                                  const float* __restrict__ val, const int* __restrict__ base,
                                  int2* __restrict__ stage, int n_edges, int nb, int nblk) {
    __shared__ int cur[2048];
    int blk = blockIdx.x;
    for (int i = threadIdx.x; i < nb; i += blockDim.x)
        cur[i] = base[i * nblk + blk];
    __syncthreads();
    int s = blk * CHUNK;
    int e = min(s + CHUNK, n_edges);
    for (int k = s + threadIdx.x; k < e; k += blockDim.x) {
        int r = row[k];
        int b = r >> RB_SHIFT;
        int pos = atomicAdd(&cur[b], 1);
        stage[pos] = make_int2(col[k] | ((r & (RB - 1)) << COL_BITS), __float_as_int(val[k]));
    }
}

// per-bucket: sort edges by row within the bucket span, emit row offsets
__global__ void bucket_finalize_kernel(const int* __restrict__ base, int nblk,
                                       const int2* __restrict__ stage,
                                       int* __restrict__ offsets,
                                       int2* __restrict__ pairs,
                                       int n_total, int n_edges) {
    __shared__ int sc[RB];
    __shared__ int cur[RB];
    int b = blockIdx.x;
    int tid = threadIdx.x;
    int s = base[b * nblk];
    int e_end = base[(b + 1) * nblk];
    if (tid < RB) sc[tid] = 0;
    __syncthreads();
    for (int k = s + tid; k < e_end; k += blockDim.x)
        atomicAdd(&sc[stage[k].x >> COL_BITS], 1);
    __syncthreads();
    for (int off = 1; off < RB; off <<= 1) {
        int v = (tid < RB && tid >= off) ? sc[tid - off] : 0;
        __syncthreads();
        if (tid < RB) sc[tid] += v;
        __syncthreads();
    }
    if (tid < RB) {
        int excl = (tid == 0) ? 0 : sc[tid - 1];
        int r = b * RB + tid;
        if (r < n_total) offsets[r] = s + excl;
        cur[tid] = s + excl;
    }
    __syncthreads();
    for (int k = s + tid; k < e_end; k += blockDim.x) {
        int2 p = stage[k];
        int rl = p.x >> COL_BITS;
        int pos = atomicAdd(&cur[rl], 1);
        pairs[pos] = make_int2(p.x & COL_MASK, p.y);
    }
    if (b == 0 && tid == 0) offsets[n_total] = n_edges;
}

// ---------------------------------------------------------------------------
// gather spmm (bf16 src/dst, f32 accum): one wave per row; 8 edge-groups of
// 8 lanes; each lane loads 16 B (8 bf16) of the 128 B row. No atomics.
__global__ void spmm_gather_kernel(const int* __restrict__ offsets,
                                   const int2* __restrict__ pairs,
                                   const unsigned short* __restrict__ src,
                                   unsigned short* __restrict__ dst, int n_total) {
    int wid = threadIdx.x >> 6;
    int lane = threadIdx.x & 63;
    int r = blockIdx.x * 4 + wid;
    if (r >= n_total) return;
    int start = offsets[r];
    int end = offsets[r + 1];
    int g = lane >> 3;       // edge slot (8 in parallel)
    int sub = lane & 7;      // 16 B sub-segment of the row
    float acc[8] = {0.f, 0.f, 0.f, 0.f, 0.f, 0.f, 0.f, 0.f};
    for (int k = start + g; k < end; k += 8) {
        int2 p = pairs[k];
        float w = __int_as_float(p.y);
        uint4 raw = reinterpret_cast<const uint4*>(src + (size_t)p.x * D)[sub];
        acc[0] += w * bf2f(raw.x & 0xffff);
        acc[1] += w * bf2f(raw.x >> 16);
        acc[2] += w * bf2f(raw.y & 0xffff);
        acc[3] += w * bf2f(raw.y >> 16);
        acc[4] += w * bf2f(raw.z & 0xffff);
        acc[5] += w * bf2f(raw.z >> 16);
        acc[6] += w * bf2f(raw.w & 0xffff);
        acc[7] += w * bf2f(raw.w >> 16);
    }
#pragma unroll
    for (int off = 8; off < 64; off <<= 1) {
#pragma unroll
        for (int i = 0; i < 8; ++i)
            acc[i] += __shfl_xor(acc[i], off, 64);
    }
    if (g == 0) {
        uint4 o;
        o.x = f2bf(acc[0]) | (f2bf(acc[1]) << 16);
        o.y = f2bf(acc[2]) | (f2bf(acc[3]) << 16);
        o.z = f2bf(acc[4]) | (f2bf(acc[5]) << 16);
        o.w = f2bf(acc[6]) | (f2bf(acc[7]) << 16);
        reinterpret_cast<uint4*>(dst + (size_t)r * D)[sub] = o;
    }
}

// ---------------------------------------------------------------------------
// layer 0: write batch rows straight from the f32 source tables
__global__ void gather_init_kernel(const int* __restrict__ users,
                                   const int* __restrict__ items,
                                   const float* __restrict__ user_emb,
                                   const float* __restrict__ item_emb,
                                   float* __restrict__ u_acc,
                                   float* __restrict__ v_acc, int batch) {
    int t = blockIdx.x * blockDim.x + threadIdx.x;
    int b = t >> 4;
    int sub = t & 15;
    if (b >= batch) return;
    reinterpret_cast<float4*>(u_acc)[(size_t)b * 16 + sub] =
        reinterpret_cast<const float4*>(user_emb)[(size_t)users[b] * 16 + sub];
    reinterpret_cast<float4*>(v_acc)[(size_t)b * 16 + sub] =
        reinterpret_cast<const float4*>(item_emb)[(size_t)items[b] * 16 + sub];
}

// layers 1,2: accumulate batch rows from bf16 buf into f32 acc
__global__ void gather_acc_kernel(const int* __restrict__ users,
                                  const int* __restrict__ items,
                                  const unsigned short* __restrict__ buf,
                                  float* __restrict__ u_acc,
                                  float* __restrict__ v_acc,
                                  int batch, int n_user_rows) {
    int t = blockIdx.x * blockDim.x + threadIdx.x;
    int b = t >> 4;
    int sub = t & 15;
    if (b >= batch) return;
    uint2 ur = reinterpret_cast<const uint2*>(buf + (size_t)users[b] * D)[sub];
    uint2 vr = reinterpret_cast<const uint2*>(buf + (size_t)(n_user_rows + items[b]) * D)[sub];
    float4* up = reinterpret_cast<float4*>(u_acc) + (size_t)b * 16 + sub;
    float4* vp = reinterpret_cast<float4*>(v_acc) + (size_t)b * 16 + sub;
    float4 a = *up, c = *vp;
    a.x += bf2f(ur.x & 0xffff); a.y += bf2f(ur.x >> 16);
    a.z += bf2f(ur.y & 0xffff); a.w += bf2f(ur.y >> 16);
    c.x += bf2f(vr.x & 0xffff); c.y += bf2f(vr.x >> 16);
    c.z += bf2f(vr.y & 0xffff); c.w += bf2f(vr.y >> 16);
    *up = a;
    *vp = c;
}

// layer 3 gather fused with dot + BCE loss
__global__ void gather_loss_kernel(const int* __restrict__ users,
                                   const int* __restrict__ items,
                                   const unsigned short* __restrict__ buf,
                                   const float* __restrict__ u_acc,
                                   const float* __restrict__ v_acc,
                                   const float* __restrict__ labels,
                                   float* __restrict__ out,
                                   int batch, int n_user_rows) {
    int t = blockIdx.x * blockDim.x + threadIdx.x;
    int b = t >> 4;
    int sub = t & 15;
    float partial = 0.0f;
    if (b < batch) {
        uint2 ur = reinterpret_cast<const uint2*>(buf + (size_t)users[b] * D)[sub];
        uint2 vr = reinterpret_cast<const uint2*>(buf + (size_t)(n_user_rows + items[b]) * D)[sub];
        float4 a = reinterpret_cast<const float4*>(u_acc)[(size_t)b * 16 + sub];
        float4 c = reinterpret_cast<const float4*>(v_acc)[(size_t)b * 16 + sub];
        a.x += bf2f(ur.x & 0xffff); a.y += bf2f(ur.x >> 16);
        a.z += bf2f(ur.y & 0xffff); a.w += bf2f(ur.y >> 16);
        c.x += bf2f(vr.x & 0xffff); c.y += bf2f(vr.x >> 16);
        c.z += bf2f(vr.y & 0xffff); c.w += bf2f(vr.y >> 16);
        partial = a.x * c.x + a.y * c.y + a.z * c.z + a.w * c.w;
    }
    partial += __shfl_xor(partial, 1, 64);
    partial += __shfl_xor(partial, 2, 64);
    partial += __shfl_xor(partial, 4, 64);
    partial += __shfl_xor(partial, 8, 64);
    float lb = 0.0f;
    if (b < batch && sub == 0) {
        float g = partial * (1.0f / 16.0f);
        float y = labels[b];
        lb = fmaxf(g, 0.0f) - g * y + log1pf(expf(-fabsf(g)));
    }
    lb += __shfl_xor(lb, 16, 64);
    lb += __shfl_xor(lb, 32, 64);
    __shared__ float sd[4];
    int wid = threadIdx.x >> 6;
    if ((threadIdx.x & 63) == 0) sd[wid] = lb;
    __syncthreads();
    if (threadIdx.x == 0)
        atomicAdd(out, (sd[0] + sd[1] + sd[2] + sd[3]) / (float)batch);
}

// ---------------------------------------------------------------------------
extern "C" void kernel_launch(void* const* d_in, const int* in_sizes, int n_in,
                              void* d_out, int out_size, void* d_ws, size_t ws_size,
                              hipStream_t stream) {
    const int* users = (const int*)d_in[0];
    const int* items = (const int*)d_in[1];
    const float* labels = (const float*)d_in[2];
    const int* edge_row = (const int*)d_in[3];
    const int* edge_col = (const int*)d_in[4];
    const float* edge_val = (const float*)d_in[5];
    const float* user_emb = (const float*)d_in[6];
    const float* item_emb = (const float*)d_in[7];

    const int batch = in_sizes[0];
    const int n_edges = in_sizes[3];
    const int n_user_rows = in_sizes[6] / D;   // 100001
    const int n_item_rows = in_sizes[7] / D;   // 50000
    const int n_total = n_user_rows + n_item_rows;
    const int nb = (n_total + RB - 1) / RB;          // 1172
    const int nblk = (n_edges + CHUNK - 1) / CHUNK;  // 123
    const int L = nb * nblk;                          // 144156

    auto align256 = [](size_t x) { return (x + 255) & ~(size_t)255; };
    const size_t tblb_bytes = align256((size_t)n_total * D * 2);            // 19.2 MB bf16
    const size_t acc_bytes = align256((size_t)batch * D * sizeof(float));   // 2 MB
    const size_t off_bytes = align256((size_t)(n_total + 1) * sizeof(int)); // 600 KB
    const size_t pairs_bytes = align256((size_t)n_edges * sizeof(int2));    // 16 MB
    const size_t base_bytes = align256((size_t)(L + 1) * sizeof(int));      // 577 KB

    char* ws = (char*)d_ws;
    unsigned short* tbl  = (unsigned short*)ws;  ws += tblb_bytes;
    unsigned short* buf0 = (unsigned short*)ws;  ws += tblb_bytes;
    unsigned short* buf1 = (unsigned short*)ws;  ws += tblb_bytes;
    float* u_acc  = (float*)ws;                  ws += acc_bytes;
    float* v_acc  = (float*)ws;                  ws += acc_bytes;
    int*   offsets= (int*)ws;                    ws += off_bytes;
    int2*  pairs  = (int2*)ws;                   ws += pairs_bytes;
    // stage (16 MB) dead before spmm layer 1 writes buf0 -> alias
    int2*  stage  = (int2*)buf0;
    // base/bsums dead before spmm layer 2 writes buf1 -> alias
    int*   base   = (int*)buf1;
    int*   bsums  = (int*)((char*)buf1 + base_bytes);

    hipMemsetAsync(d_out, 0, sizeof(float) * out_size, stream);

    // ---- bf16 table conversion ----
    convert_kernel<<<2048, 256, 0, stream>>>(user_emb, item_emb, tbl, n_user_rows, n_total);

    // ---- CSR build: exact-offset two-level binning, no global atomics ----
    hist2_kernel<<<nblk, 256, 0, stream>>>(edge_row, base, n_edges, nb, nblk);
    const int nscan = (L + SCAN_CHUNK - 1) / SCAN_CHUNK;
    scan_block_kernel<<<nscan, 256, 0, stream>>>(base, bsums, L);
    scan_sums_kernel<<<1, 64, 0, stream>>>(bsums, nscan, base, L);
    scan_add_kernel<<<(L + 255) / 256, 256, 0, stream>>>(base, bsums, L);
    fill_exact_kernel<<<nblk, 256, 0, stream>>>(edge_row, edge_col, edge_val,
                                                base, stage, n_edges, nb, nblk);
    bucket_finalize_kernel<<<nb, 256, 0, stream>>>(base, nblk, stage, offsets, pairs,
                                                   n_total, n_edges);

    // ---- layer 0 batch gather ----
    const int ga_blocks = (batch * 16 + 255) / 256;
    gather_init_kernel<<<ga_blocks, 256, 0, stream>>>(users, items, user_emb, item_emb,
                                                      u_acc, v_acc, batch);

    // ---- 3 propagation layers (bf16 gather, f32 accumulate) ----
    const int rows_blocks = (n_total + 3) / 4;
    spmm_gather_kernel<<<rows_blocks, 256, 0, stream>>>(offsets, pairs, tbl, buf0, n_total);
    gather_acc_kernel<<<ga_blocks, 256, 0, stream>>>(users, items, buf0,
                                                     u_acc, v_acc, batch, n_user_rows);
    spmm_gather_kernel<<<rows_blocks, 256, 0, stream>>>(offsets, pairs, buf0, buf1, n_total);
    gather_acc_kernel<<<ga_blocks, 256, 0, stream>>>(users, items, buf1,
                                                     u_acc, v_acc, batch, n_user_rows);
    spmm_gather_kernel<<<rows_blocks, 256, 0, stream>>>(offsets, pairs, buf1, buf0, n_total);
    gather_loss_kernel<<<ga_blocks, 256, 0, stream>>>(users, items, buf0, u_acc, v_acc,
                                                      labels, (float*)d_out,
                                                      batch, n_user_rows);
}